// Round 4
// baseline (1202.964 us; speedup 1.0000x reference)
//
#include <hip/hip_runtime.h>
#include <hip/hip_bf16.h>
#include <cstdint>
#include <cstddef>

#define N_NODES 50000
#define N_EDGES 600000
#define DF 128
#define N_ETYPES 4
#define N_STEPS 5
#define SCAN_NB 196        // ceil(50000/256)
#define GRU_BX 128         // grid.x; total blocks = 128*2 = 256 = 1/CU
#define GRU_TILES 3125     // 50000/16 exact

typedef _Float16 f16x8 __attribute__((ext_vector_type(8)));
typedef _Float16 f16x4 __attribute__((ext_vector_type(4)));
typedef _Float16 f16x2 __attribute__((ext_vector_type(2)));
typedef float f32x4 __attribute__((ext_vector_type(4)));

__device__ __forceinline__ float sigmoid_fast(float x) {
    return 1.0f / (1.0f + __expf(-x));
}
__device__ __forceinline__ float tanh_fast(float x) {
    return 1.0f - 2.0f / (__expf(2.0f * x) + 1.0f);
}
// load 8 consecutive fp32 and round to f16x8 (MFMA A-frag helper)
__device__ __forceinline__ f16x8 cvt8(const float* p) {
    float4 u = *(const float4*)p;
    float4 v = *(const float4*)(p + 4);
    f16x8 r;
    r[0] = (_Float16)u.x; r[1] = (_Float16)u.y;
    r[2] = (_Float16)u.z; r[3] = (_Float16)u.w;
    r[4] = (_Float16)v.x; r[5] = (_Float16)v.y;
    r[6] = (_Float16)v.z; r[7] = (_Float16)v.w;
    return r;
}

// ---------------- setup kernels (once per launch) ----------------

// Wl -> f16; build concatenated GRU B matrix Bc[g*128+c][k]: k<128 -> wih, else whh
__global__ __launch_bounds__(256) void k_cvt_w(
    const float* __restrict__ Wl, const float* __restrict__ wih,
    const float* __restrict__ whh, _Float16* __restrict__ Wl_h,
    _Float16* __restrict__ Bc) {
    int i = blockIdx.x * 256 + threadIdx.x;          // grid covers 98304
    if (i < N_ETYPES * DF * DF) Wl_h[i] = (_Float16)Wl[i];
    int row = i >> 8;                                // 0..383 = g*128 + c
    int k = i & 255;
    float v = (k < 128) ? wih[row * 128 + k] : whh[row * 128 + (k - 128)];
    Bc[i] = (_Float16)v;
}

__global__ __launch_bounds__(256) void k_hist(
    const int* __restrict__ dst, int* __restrict__ deg, int E) {
    int i = blockIdx.x * 256 + threadIdx.x;
    if (i < E) atomicAdd(&deg[dst[i]], 1);
}

// hierarchical exclusive scan over deg[0..N)
__global__ __launch_bounds__(256) void k_part(
    const int* __restrict__ deg, int* __restrict__ part, int N) {
    __shared__ int s[256];
    int t = threadIdx.x, i = blockIdx.x * 256 + t;
    s[t] = (i < N) ? deg[i] : 0;
    __syncthreads();
    for (int off = 128; off > 0; off >>= 1) {
        if (t < off) s[t] += s[t + off];
        __syncthreads();
    }
    if (t == 0) part[blockIdx.x] = s[0];
}

__global__ __launch_bounds__(256) void k_scan1(int* __restrict__ part, int nb) {
    __shared__ int s[256];
    int t = threadIdx.x;
    int v = (t < nb) ? part[t] : 0;
    s[t] = v;
    __syncthreads();
    for (int off = 1; off < 256; off <<= 1) {
        int u = (t >= off) ? s[t - off] : 0;
        __syncthreads();
        s[t] += u;
        __syncthreads();
    }
    if (t < nb) part[t] = s[t] - v;
}

__global__ __launch_bounds__(256) void k_row(
    const int* __restrict__ deg, const int* __restrict__ part,
    int* __restrict__ row_start, int* __restrict__ cursor, int N) {
    __shared__ int s[256];
    int t = threadIdx.x, i = blockIdx.x * 256 + t;
    int d = (i < N) ? deg[i] : 0;
    s[t] = d;
    __syncthreads();
    for (int off = 1; off < 256; off <<= 1) {
        int u = (t >= off) ? s[t - off] : 0;
        __syncthreads();
        s[t] += u;
        __syncthreads();
    }
    int rs = part[blockIdx.x] + s[t] - d;
    if (i < N) {
        row_start[i] = rs;
        cursor[i] = rs;
        if (i == N - 1) row_start[N] = rs + d;
    }
}

__global__ __launch_bounds__(256) void k_fill(
    const int* __restrict__ src, const int* __restrict__ dst,
    const int* __restrict__ ety, int* __restrict__ cursor,
    int* __restrict__ csr, int E) {
    int i = blockIdx.x * 256 + threadIdx.x;
    if (i < E) {
        int slot = atomicAdd(&cursor[dst[i]], 1);
        csr[slot] = src[i] | ((ety[i] - 1) << 16);   // src < 65536, et in 0..3
    }
}

// ---------------- per-step kernels ----------------

// t[k][n][f] = sum_d h[n,d] * W[k][f,d] + b_lin[k][f]   (fp32 h in, f16 out)
__global__ __launch_bounds__(256) void k_lin(
    const float* __restrict__ h, const _Float16* __restrict__ Wl,
    const float* __restrict__ b_lin, _Float16* __restrict__ t_out, int N) {
    const int wave = threadIdx.x >> 6, lane = threadIdx.x & 63;
    const int col = lane & 15, quad = lane >> 4;
    const int r0 = blockIdx.x * 64 + wave * 16;
    int arow = r0 + col; if (arow >= N) arow = N - 1;
    f16x8 a[4];
    const float* hp = h + (size_t)arow * DF + quad * 8;
#pragma unroll
    for (int kt = 0; kt < 4; kt++) a[kt] = cvt8(hp + kt * 32);
#pragma unroll
    for (int ktype = 0; ktype < N_ETYPES; ktype++) {
        const _Float16* W = Wl + (size_t)ktype * DF * DF;
        _Float16* tk = t_out + (size_t)ktype * N * DF;
#pragma unroll
        for (int ft = 0; ft < 8; ft++) {
            f32x4 acc = {0.f, 0.f, 0.f, 0.f};
            const _Float16* wrow = W + (size_t)(ft * 16 + col) * DF + quad * 8;
#pragma unroll
            for (int kt = 0; kt < 4; kt++)
                acc = __builtin_amdgcn_mfma_f32_16x16x32_f16(
                    a[kt], *(const f16x8*)(wrow + kt * 32), acc, 0, 0, 0);
            float bias = b_lin[ktype * DF + ft * 16 + col];
#pragma unroll
            for (int i = 0; i < 4; i++) {
                int row = r0 + quad * 4 + i;
                if (row < N)
                    tk[(size_t)row * DF + ft * 16 + col] = (_Float16)(acc[i] + bias);
            }
        }
    }
}

// a[n][:] = sum over incoming edges of t[et][src][:]  -> f16
// wave = 4 edge-slots x 16 lanes; each lane loads f16x8 (16B) = 8 cols.
// 8 edges in flight per iteration; shfl_xor butterfly reduce at the end.
__global__ __launch_bounds__(256) void k_agg(
    const _Float16* __restrict__ t, const int* __restrict__ row_start,
    const int* __restrict__ csr, _Float16* __restrict__ ah, int N) {
    const int wave = threadIdx.x >> 6, lane = threadIdx.x & 63;
    const int g4 = lane >> 4;                        // edge slot 0..3
    const int c8 = lane & 15;                        // col chunk: cols c8*8..+7
    const int n = blockIdx.x * 4 + wave;             // grid = N/4 exactly
    const int beg = row_start[n], end = row_start[n + 1];
    float acc[8] = {0.f, 0.f, 0.f, 0.f, 0.f, 0.f, 0.f, 0.f};
    for (int e = beg; e < end; e += 8) {
        int i0 = e + g4, i1 = e + 4 + g4;
        float m0 = (i0 < end) ? 1.0f : 0.0f;
        float m1 = (i1 < end) ? 1.0f : 0.0f;
        int j0 = (i0 < end) ? i0 : end - 1;
        int j1 = (i1 < end) ? i1 : end - 1;
        int p0 = csr[j0], p1 = csr[j1];
        f16x8 x0 = *(const f16x8*)(t + ((((size_t)(p0 >> 16)) * N + (p0 & 0xFFFF)) << 7) + c8 * 8);
        f16x8 x1 = *(const f16x8*)(t + ((((size_t)(p1 >> 16)) * N + (p1 & 0xFFFF)) << 7) + c8 * 8);
#pragma unroll
        for (int j = 0; j < 8; j++) acc[j] += m0 * (float)x0[j];
#pragma unroll
        for (int j = 0; j < 8; j++) acc[j] += m1 * (float)x1[j];
    }
#pragma unroll
    for (int j = 0; j < 8; j++) {
        acc[j] += __shfl_xor(acc[j], 32, 64);
        acc[j] += __shfl_xor(acc[j], 16, 64);
    }
    if (lane < 16) {
        f16x8 o;
#pragma unroll
        for (int j = 0; j < 8; j++) o[j] = (_Float16)acc[j];
        *(f16x8*)(ah + ((size_t)n << 7) + c8 * 8) = o;
    }
}

// GRU with concat-K (K=256, A=[a|h]), LDS-resident weights in frag-major layout.
// grid (128,2): blockIdx.y = col-group of 64; block = 1024 thr = 16 waves, 1 block/CU.
// Wave task = 16 rows x 32 cols; adjacent waves (2w,2w+1) take the two col-halves
// of the same row-tile so the A re-read is L1/L2-hot.
__global__ __launch_bounds__(1024, 4) void k_gru(
    const _Float16* __restrict__ ah, const float* __restrict__ h_in,
    const _Float16* __restrict__ Bc, const float* __restrict__ b_ih,
    const float* __restrict__ b_hh, float* __restrict__ h_out, int N) {
    __shared__ _Float16 Bs[49152];                   // 96 frags x 512 f16 = 96 KB
    const int wave = threadIdx.x >> 6, lane = threadIdx.x & 63;
    const int col16 = lane & 15, quad = lane >> 4;
    const int cg = blockIdx.y;
    const int half = wave & 1, pair = wave >> 1;

    // stage B: frag-major. cid -> [g][ct4][kt][c16][q], 8 f16 each.
    for (int j = 0; j < 6; j++) {
        int cid = threadIdx.x + j * 1024;            // 0..6143
        int q = cid & 3, c16 = (cid >> 2) & 15, kt = (cid >> 6) & 7;
        int ct4 = (cid >> 9) & 3, g = cid >> 11;
        int row = g * 128 + cg * 64 + ct4 * 16 + c16;
        const _Float16* gp = Bc + ((size_t)row << 8) + kt * 32 + q * 8;
        *(f16x8*)&Bs[cid * 8] = *(const f16x8*)gp;
    }
    __syncthreads();

    for (int tile = blockIdx.x * 8 + pair; tile < GRU_TILES; tile += GRU_BX * 8) {
        const int r0 = tile * 16;
        const int arow = r0 + col16;                 // < 50000 always (3125*16 exact)
        f16x8 A[8];                                  // kt<4 = a, kt>=4 = h
        const _Float16* ap = ah + ((size_t)arow << 7) + quad * 8;
        const float* hp = h_in + ((size_t)arow << 7) + quad * 8;
#pragma unroll
        for (int kt = 0; kt < 4; kt++) A[kt] = *(const f16x8*)(ap + kt * 32);
#pragma unroll
        for (int kt = 0; kt < 4; kt++) A[4 + kt] = cvt8(hp + kt * 32);

        f32x4 acc[4][2];                             // [set r,z,in,hn][ct]
#pragma unroll
        for (int s = 0; s < 4; s++)
#pragma unroll
            for (int ct = 0; ct < 2; ct++) acc[s][ct] = (f32x4){0.f, 0.f, 0.f, 0.f};

#pragma unroll
        for (int g = 0; g < 3; g++)
#pragma unroll
            for (int ct = 0; ct < 2; ct++) {
                const int fbase = ((g * 4 + half * 2 + ct) * 8) * 512 + (col16 * 4 + quad) * 8;
#pragma unroll
                for (int kt = 0; kt < 8; kt++) {
                    f16x8 b = *(const f16x8*)&Bs[fbase + kt * 512];
                    const int set = (g < 2) ? g : (kt < 4 ? 2 : 3);
                    acc[set][ct] = __builtin_amdgcn_mfma_f32_16x16x32_f16(
                        A[kt], b, acc[set][ct], 0, 0, 0);
                }
            }
#pragma unroll
        for (int ct = 0; ct < 2; ct++) {
            const int c = cg * 64 + half * 32 + ct * 16 + col16;
            const float bR = b_ih[c] + b_hh[c];
            const float bZ = b_ih[128 + c] + b_hh[128 + c];
            const float bIN = b_ih[256 + c];
            const float bHN = b_hh[256 + c];
#pragma unroll
            for (int i = 0; i < 4; i++) {
                const int row = r0 + quad * 4 + i;
                float r = sigmoid_fast(acc[0][ct][i] + bR);
                float z = sigmoid_fast(acc[1][ct][i] + bZ);
                float nn = tanh_fast(acc[2][ct][i] + bIN + r * (acc[3][ct][i] + bHN));
                size_t idx = ((size_t)row << 7) + c;
                h_out[idx] = (1.f - z) * nn + z * h_in[idx];
            }
        }
    }
}

// ---------------- launch ----------------

extern "C" void kernel_launch(void* const* d_in, const int* in_sizes, int n_in,
                              void* d_out, int out_size, void* d_ws, size_t ws_size,
                              hipStream_t stream) {
    const float* h0    = (const float*)d_in[0];
    const int*   src   = (const int*)d_in[1];
    const int*   dst   = (const int*)d_in[2];
    const int*   ety   = (const int*)d_in[3];
    const float* W_lin = (const float*)d_in[4];
    const float* b_lin = (const float*)d_in[5];
    const float* w_ih  = (const float*)d_in[6];
    const float* w_hh  = (const float*)d_in[7];
    const float* b_ih  = (const float*)d_in[8];
    const float* b_hh  = (const float*)d_in[9];
    float* hout = (float*)d_out;

    char* p = (char*)d_ws;
    auto alloc = [&](size_t bytes) -> char* {
        char* r = p;
        p += (bytes + 255) & ~(size_t)255;
        return r;
    };
    float*    h_ws   = (float*)alloc((size_t)N_NODES * DF * 4);
    _Float16* a_half = (_Float16*)alloc((size_t)N_NODES * DF * 2);
    _Float16* t_half = (_Float16*)alloc((size_t)N_ETYPES * N_NODES * DF * 2);
    _Float16* Wl_h   = (_Float16*)alloc((size_t)N_ETYPES * DF * DF * 2);
    _Float16* Bc     = (_Float16*)alloc((size_t)3 * DF * 2 * DF * 2);   // [384][256] f16
    int* deg       = (int*)alloc((size_t)N_NODES * 4);
    int* row_start = (int*)alloc((size_t)(N_NODES + 1) * 4);
    int* cursor    = (int*)alloc((size_t)N_NODES * 4);
    int* csr       = (int*)alloc((size_t)N_EDGES * 4);
    int* part      = (int*)alloc((size_t)SCAN_NB * 4);

    hipMemsetAsync(deg, 0, (size_t)N_NODES * 4, stream);
    k_cvt_w<<<384, 256, 0, stream>>>(W_lin, w_ih, w_hh, Wl_h, Bc);
    k_hist<<<(N_EDGES + 255) / 256, 256, 0, stream>>>(dst, deg, N_EDGES);
    k_part<<<SCAN_NB, 256, 0, stream>>>(deg, part, N_NODES);
    k_scan1<<<1, 256, 0, stream>>>(part, SCAN_NB);
    k_row<<<SCAN_NB, 256, 0, stream>>>(deg, part, row_start, cursor, N_NODES);
    k_fill<<<(N_EDGES + 255) / 256, 256, 0, stream>>>(src, dst, ety, cursor, csr, N_EDGES);

    // fp32 h ping-pong: writes land in d_out on steps 0,2,4 (final in d_out);
    // in != out every step so k_gru's A reads never race its writes.
    const float* cur = h0;
    const int nb = (N_NODES + 63) / 64;              // 782
    for (int s = 0; s < N_STEPS; s++) {
        k_lin<<<nb, 256, 0, stream>>>(cur, Wl_h, b_lin, t_half, N_NODES);
        k_agg<<<N_NODES / 4, 256, 0, stream>>>(t_half, row_start, csr, a_half, N_NODES);
        float* nxt = (s & 1) ? h_ws : hout;
        k_gru<<<dim3(GRU_BX, 2), 1024, 0, stream>>>(a_half, cur, Bc, b_ih, b_hh, nxt, N_NODES);
        cur = nxt;
    }
}

// Round 5
// 922.315 us; speedup vs baseline: 1.3043x; 1.3043x over previous
//
#include <hip/hip_runtime.h>
#include <hip/hip_bf16.h>
#include <cstdint>
#include <cstddef>

#define N_NODES 50000
#define N_EDGES 600000
#define DF 128
#define N_ETYPES 4
#define N_STEPS 5
#define SCAN_NB 196        // ceil(50000/256)
#define GRU_TILES 3125     // 50000/16 exact
#define GRU_BLOCKS 256     // 1 block/CU
#define LSTRIDE 130        // LDS row stride in floats: (4*130)%32=8 -> 2-way only (free)

typedef _Float16 f16x8 __attribute__((ext_vector_type(8)));
typedef _Float16 f16x4 __attribute__((ext_vector_type(4)));
typedef _Float16 f16x2 __attribute__((ext_vector_type(2)));
typedef float f32x4 __attribute__((ext_vector_type(4)));

__device__ __forceinline__ float sigmoid_fast(float x) {
    return 1.0f / (1.0f + __expf(-x));
}
__device__ __forceinline__ float tanh_fast(float x) {
    return 1.0f - 2.0f / (__expf(2.0f * x) + 1.0f);
}

// ---------------- setup kernels (once per launch) ----------------

// Wl -> f16; build concatenated GRU B matrix Bc[g*128+c][k]: k<128 -> wih, else whh
__global__ __launch_bounds__(256) void k_cvt_w(
    const float* __restrict__ Wl, const float* __restrict__ wih,
    const float* __restrict__ whh, _Float16* __restrict__ Wl_h,
    _Float16* __restrict__ Bc) {
    int i = blockIdx.x * 256 + threadIdx.x;          // grid covers 98304
    if (i < N_ETYPES * DF * DF) Wl_h[i] = (_Float16)Wl[i];
    int row = i >> 8;                                // 0..383 = g*128 + c
    int k = i & 255;
    float v = (k < 128) ? wih[row * 128 + k] : whh[row * 128 + (k - 128)];
    Bc[i] = (_Float16)v;
}

__global__ __launch_bounds__(256) void k_cvt_h(
    const float* __restrict__ h, _Float16* __restrict__ hh, int n4) {
    int i = blockIdx.x * 256 + threadIdx.x;
    if (i < n4) {
        float4 v = ((const float4*)h)[i];
        f16x4 o;
        o.x = (_Float16)v.x; o.y = (_Float16)v.y;
        o.z = (_Float16)v.z; o.w = (_Float16)v.w;
        ((f16x4*)hh)[i] = o;
    }
}

__global__ __launch_bounds__(256) void k_hist(
    const int* __restrict__ dst, int* __restrict__ deg, int E) {
    int i = blockIdx.x * 256 + threadIdx.x;
    if (i < E) atomicAdd(&deg[dst[i]], 1);
}

// hierarchical exclusive scan over deg[0..N)
__global__ __launch_bounds__(256) void k_part(
    const int* __restrict__ deg, int* __restrict__ part, int N) {
    __shared__ int s[256];
    int t = threadIdx.x, i = blockIdx.x * 256 + t;
    s[t] = (i < N) ? deg[i] : 0;
    __syncthreads();
    for (int off = 128; off > 0; off >>= 1) {
        if (t < off) s[t] += s[t + off];
        __syncthreads();
    }
    if (t == 0) part[blockIdx.x] = s[0];
}

__global__ __launch_bounds__(256) void k_scan1(int* __restrict__ part, int nb) {
    __shared__ int s[256];
    int t = threadIdx.x;
    int v = (t < nb) ? part[t] : 0;
    s[t] = v;
    __syncthreads();
    for (int off = 1; off < 256; off <<= 1) {
        int u = (t >= off) ? s[t - off] : 0;
        __syncthreads();
        s[t] += u;
        __syncthreads();
    }
    if (t < nb) part[t] = s[t] - v;
}

__global__ __launch_bounds__(256) void k_row(
    const int* __restrict__ deg, const int* __restrict__ part,
    int* __restrict__ row_start, int* __restrict__ cursor, int N) {
    __shared__ int s[256];
    int t = threadIdx.x, i = blockIdx.x * 256 + t;
    int d = (i < N) ? deg[i] : 0;
    s[t] = d;
    __syncthreads();
    for (int off = 1; off < 256; off <<= 1) {
        int u = (t >= off) ? s[t - off] : 0;
        __syncthreads();
        s[t] += u;
        __syncthreads();
    }
    int rs = part[blockIdx.x] + s[t] - d;
    if (i < N) {
        row_start[i] = rs;
        cursor[i] = rs;
        if (i == N - 1) row_start[N] = rs + d;
    }
}

__global__ __launch_bounds__(256) void k_fill(
    const int* __restrict__ src, const int* __restrict__ dst,
    const int* __restrict__ ety, int* __restrict__ cursor,
    int* __restrict__ csr, int E) {
    int i = blockIdx.x * 256 + threadIdx.x;
    if (i < E) {
        int slot = atomicAdd(&cursor[dst[i]], 1);
        csr[slot] = src[i] | ((ety[i] - 1) << 16);   // src < 65536, et in 0..3
    }
}

// ---------------- per-step kernels ----------------

// t[k][n][f] = sum_d h[n,d] * W[k][f,d] + b_lin[k][f]   (f16 h in, f16 out)
__global__ __launch_bounds__(256) void k_lin(
    const _Float16* __restrict__ hh, const _Float16* __restrict__ Wl,
    const float* __restrict__ b_lin, _Float16* __restrict__ t_out, int N) {
    const int wave = threadIdx.x >> 6, lane = threadIdx.x & 63;
    const int col = lane & 15, quad = lane >> 4;
    const int r0 = blockIdx.x * 64 + wave * 16;
    int arow = r0 + col; if (arow >= N) arow = N - 1;
    f16x8 a[4];
    const _Float16* hp = hh + (size_t)arow * DF + quad * 8;
#pragma unroll
    for (int kt = 0; kt < 4; kt++) a[kt] = *(const f16x8*)(hp + kt * 32);
#pragma unroll
    for (int ktype = 0; ktype < N_ETYPES; ktype++) {
        const _Float16* W = Wl + (size_t)ktype * DF * DF;
        _Float16* tk = t_out + (size_t)ktype * N * DF;
#pragma unroll
        for (int ft = 0; ft < 8; ft++) {
            f32x4 acc = {0.f, 0.f, 0.f, 0.f};
            const _Float16* wrow = W + (size_t)(ft * 16 + col) * DF + quad * 8;
#pragma unroll
            for (int kt = 0; kt < 4; kt++)
                acc = __builtin_amdgcn_mfma_f32_16x16x32_f16(
                    a[kt], *(const f16x8*)(wrow + kt * 32), acc, 0, 0, 0);
            float bias = b_lin[ktype * DF + ft * 16 + col];
#pragma unroll
            for (int i = 0; i < 4; i++) {
                int row = r0 + quad * 4 + i;
                if (row < N)
                    tk[(size_t)row * DF + ft * 16 + col] = (_Float16)(acc[i] + bias);
            }
        }
    }
}

// a[n][:] = sum over incoming edges of t[et][src][:]  -> f16
// wave = 4 edge-slots x 16 lanes; each lane loads f16x8 (16B) = 8 cols.
__global__ __launch_bounds__(256) void k_agg(
    const _Float16* __restrict__ t, const int* __restrict__ row_start,
    const int* __restrict__ csr, _Float16* __restrict__ ah, int N) {
    const int wave = threadIdx.x >> 6, lane = threadIdx.x & 63;
    const int g4 = lane >> 4;                        // edge slot 0..3
    const int c8 = lane & 15;                        // col chunk: cols c8*8..+7
    const int n = blockIdx.x * 4 + wave;             // grid = N/4 exactly
    const int beg = row_start[n], end = row_start[n + 1];
    float acc[8] = {0.f, 0.f, 0.f, 0.f, 0.f, 0.f, 0.f, 0.f};
    for (int e = beg; e < end; e += 8) {
        int i0 = e + g4, i1 = e + 4 + g4;
        float m0 = (i0 < end) ? 1.0f : 0.0f;
        float m1 = (i1 < end) ? 1.0f : 0.0f;
        int j0 = (i0 < end) ? i0 : end - 1;
        int j1 = (i1 < end) ? i1 : end - 1;
        int p0 = csr[j0], p1 = csr[j1];
        f16x8 x0 = *(const f16x8*)(t + ((((size_t)(p0 >> 16)) * N + (p0 & 0xFFFF)) << 7) + c8 * 8);
        f16x8 x1 = *(const f16x8*)(t + ((((size_t)(p1 >> 16)) * N + (p1 & 0xFFFF)) << 7) + c8 * 8);
#pragma unroll
        for (int j = 0; j < 8; j++) acc[j] += m0 * (float)x0[j];
#pragma unroll
        for (int j = 0; j < 8; j++) acc[j] += m1 * (float)x1[j];
    }
#pragma unroll
    for (int j = 0; j < 8; j++) {
        acc[j] += __shfl_xor(acc[j], 32, 64);
        acc[j] += __shfl_xor(acc[j], 16, 64);
    }
    if (lane < 16) {
        f16x8 o;
#pragma unroll
        for (int j = 0; j < 8; j++) o[j] = (_Float16)acc[j];
        *(f16x8*)(ah + ((size_t)n << 7) + c8 * 8) = o;
    }
}

// GRU, gate-parallel: one block per 16-row tile computes ALL 384 output cols.
// 12 waves = 3 gates x 4 col-slices; each wave's B-slice (2x8 frags) persistent
// in VGPRs across the grid-stride task loop. A (ah||h f16, K=256) read once per
// block. Gate accs exchanged through LDS; epilogue fuses gates -> f16 h_next
// (+ fp32 h on the final step).
__global__ __launch_bounds__(768, 3) void k_gru(
    const _Float16* __restrict__ ah, const _Float16* __restrict__ hh,
    const _Float16* __restrict__ Bc, const float* __restrict__ b_ih,
    const float* __restrict__ b_hh, _Float16* __restrict__ hh_next,
    float* __restrict__ out_f32) {
    __shared__ float X[4 * 16 * LSTRIDE];            // [set r,z,in,hn][row][col]
    const int wave = threadIdx.x >> 6, lane = threadIdx.x & 63;
    const int col16 = lane & 15, quad = lane >> 4;
    const int g = wave >> 2;                         // gate 0..2
    const int s = wave & 3;                          // col-slice of 32

    // persistent B fragments: rows (g*128 + s*32 + ct*16 + col16), k = kt*32+quad*8
    f16x8 b[2][8];
#pragma unroll
    for (int ct = 0; ct < 2; ct++) {
        const _Float16* bp = Bc + (((size_t)(g * 128 + s * 32 + ct * 16 + col16)) << 8) + quad * 8;
#pragma unroll
        for (int kt = 0; kt < 8; kt++) b[ct][kt] = *(const f16x8*)(bp + kt * 32);
    }

    for (int tile = blockIdx.x; tile < GRU_TILES; tile += GRU_BLOCKS) {
        const int r0 = tile * 16;                    // 50000 = 16*3125: no row guards
        const int arow = r0 + col16;
        f16x8 A[8];                                  // kt<4 = a, kt>=4 = h
        const _Float16* ap = ah + ((size_t)arow << 7) + quad * 8;
        const _Float16* hp = hh + ((size_t)arow << 7) + quad * 8;
#pragma unroll
        for (int kt = 0; kt < 4; kt++) A[kt] = *(const f16x8*)(ap + kt * 32);
#pragma unroll
        for (int kt = 0; kt < 4; kt++) A[4 + kt] = *(const f16x8*)(hp + kt * 32);

        f32x4 acc[2][2];                             // [khalf-set][ct]; g<2 uses set 0 only
#pragma unroll
        for (int u = 0; u < 2; u++)
#pragma unroll
            for (int ct = 0; ct < 2; ct++) acc[u][ct] = (f32x4){0.f, 0.f, 0.f, 0.f};
#pragma unroll
        for (int kt = 0; kt < 8; kt++) {
            const int set = (g == 2 && kt >= 4) ? 1 : 0;
#pragma unroll
            for (int ct = 0; ct < 2; ct++)
                acc[set][ct] = __builtin_amdgcn_mfma_f32_16x16x32_f16(
                    A[kt], b[ct][kt], acc[set][ct], 0, 0, 0);
        }

        // acc -> LDS exchange
#pragma unroll
        for (int ct = 0; ct < 2; ct++) {
            const int cbase = s * 32 + ct * 16 + col16;
            if (g < 2) {
#pragma unroll
                for (int i = 0; i < 4; i++)
                    X[g * (16 * LSTRIDE) + (quad * 4 + i) * LSTRIDE + cbase] = acc[0][ct][i];
            } else {
#pragma unroll
                for (int i = 0; i < 4; i++) {
                    X[2 * (16 * LSTRIDE) + (quad * 4 + i) * LSTRIDE + cbase] = acc[0][ct][i];
                    X[3 * (16 * LSTRIDE) + (quad * 4 + i) * LSTRIDE + cbase] = acc[1][ct][i];
                }
            }
        }
        __syncthreads();

        // epilogue: 2048 elems over 768 threads
#pragma unroll
        for (int pazz = 0; pazz < 3; pazz++) {
            int e = threadIdx.x + pazz * 768;
            if (e < 2048) {
                int row = e >> 7, col = e & 127;
                float vr = X[0 * (16 * LSTRIDE) + row * LSTRIDE + col];
                float vz = X[1 * (16 * LSTRIDE) + row * LSTRIDE + col];
                float vin = X[2 * (16 * LSTRIDE) + row * LSTRIDE + col];
                float vhn = X[3 * (16 * LSTRIDE) + row * LSTRIDE + col];
                float r = sigmoid_fast(vr + b_ih[col] + b_hh[col]);
                float z = sigmoid_fast(vz + b_ih[128 + col] + b_hh[128 + col]);
                float nn = tanh_fast(vin + b_ih[256 + col] + r * (vhn + b_hh[256 + col]));
                size_t idx = ((size_t)(r0 + row) << 7) + col;
                float hprev = (float)hh[idx];
                float hv = (1.f - z) * nn + z * hprev;
                hh_next[idx] = (_Float16)hv;
                if (out_f32) out_f32[idx] = hv;
            }
        }
        __syncthreads();                             // protect X before next tile's writes
    }
}

// ---------------- launch ----------------

extern "C" void kernel_launch(void* const* d_in, const int* in_sizes, int n_in,
                              void* d_out, int out_size, void* d_ws, size_t ws_size,
                              hipStream_t stream) {
    const float* h0    = (const float*)d_in[0];
    const int*   src   = (const int*)d_in[1];
    const int*   dst   = (const int*)d_in[2];
    const int*   ety   = (const int*)d_in[3];
    const float* W_lin = (const float*)d_in[4];
    const float* b_lin = (const float*)d_in[5];
    const float* w_ih  = (const float*)d_in[6];
    const float* w_hh  = (const float*)d_in[7];
    const float* b_ih  = (const float*)d_in[8];
    const float* b_hh  = (const float*)d_in[9];
    float* hout = (float*)d_out;

    char* p = (char*)d_ws;
    auto alloc = [&](size_t bytes) -> char* {
        char* r = p;
        p += (bytes + 255) & ~(size_t)255;
        return r;
    };
    _Float16* h_a    = (_Float16*)alloc((size_t)N_NODES * DF * 2);
    _Float16* h_b    = (_Float16*)alloc((size_t)N_NODES * DF * 2);
    _Float16* a_half = (_Float16*)alloc((size_t)N_NODES * DF * 2);
    _Float16* t_half = (_Float16*)alloc((size_t)N_ETYPES * N_NODES * DF * 2);
    _Float16* Wl_h   = (_Float16*)alloc((size_t)N_ETYPES * DF * DF * 2);
    _Float16* Bc     = (_Float16*)alloc((size_t)3 * DF * 2 * DF * 2);   // [384][256] f16
    int* deg       = (int*)alloc((size_t)N_NODES * 4);
    int* row_start = (int*)alloc((size_t)(N_NODES + 1) * 4);
    int* cursor    = (int*)alloc((size_t)N_NODES * 4);
    int* csr       = (int*)alloc((size_t)N_EDGES * 4);
    int* part      = (int*)alloc((size_t)SCAN_NB * 4);

    hipMemsetAsync(deg, 0, (size_t)N_NODES * 4, stream);
    k_cvt_w<<<384, 256, 0, stream>>>(W_lin, w_ih, w_hh, Wl_h, Bc);
    k_cvt_h<<<(N_NODES * DF / 4 + 255) / 256, 256, 0, stream>>>(h0, h_a, N_NODES * DF / 4);
    k_hist<<<(N_EDGES + 255) / 256, 256, 0, stream>>>(dst, deg, N_EDGES);
    k_part<<<SCAN_NB, 256, 0, stream>>>(deg, part, N_NODES);
    k_scan1<<<1, 256, 0, stream>>>(part, SCAN_NB);
    k_row<<<SCAN_NB, 256, 0, stream>>>(deg, part, row_start, cursor, N_NODES);
    k_fill<<<(N_EDGES + 255) / 256, 256, 0, stream>>>(src, dst, ety, cursor, csr, N_EDGES);

    _Float16* hc = h_a;
    _Float16* hn = h_b;
    const int nb = (N_NODES + 63) / 64;              // 782
    for (int s = 0; s < N_STEPS; s++) {
        k_lin<<<nb, 256, 0, stream>>>(hc, Wl_h, b_lin, t_half, N_NODES);
        k_agg<<<N_NODES / 4, 256, 0, stream>>>(t_half, row_start, csr, a_half, N_NODES);
        float* of = (s == N_STEPS - 1) ? hout : nullptr;
        k_gru<<<GRU_BLOCKS, 768, 0, stream>>>(a_half, hc, Bc, b_ih, b_hh, hn, of);
        _Float16* tmp = hc; hc = hn; hn = tmp;
    }
}

// Round 6
// 910.554 us; speedup vs baseline: 1.3211x; 1.0129x over previous
//
#include <hip/hip_runtime.h>
#include <hip/hip_bf16.h>
#include <cstdint>
#include <cstddef>

#define N_NODES 50000
#define N_EDGES 600000
#define DF 128
#define N_ETYPES 4
#define N_STEPS 5
#define SCAN_NB 196        // ceil(50000/256)
#define GRU_TILES 3125     // 50000/16 exact
#define GRU_BLOCKS 256     // 1 block/CU
#define LSTRIDE 130        // k_gru LDS row stride (floats): 2-way bank alias only (free)
#define TSTRIDE 136        // k_lin LDS tile row stride (f16)

typedef _Float16 f16x8 __attribute__((ext_vector_type(8)));
typedef _Float16 f16x4 __attribute__((ext_vector_type(4)));
typedef _Float16 f16x2 __attribute__((ext_vector_type(2)));
typedef float f32x4 __attribute__((ext_vector_type(4)));

__device__ __forceinline__ float sigmoid_fast(float x) {
    return 1.0f / (1.0f + __expf(-x));
}
__device__ __forceinline__ float tanh_fast(float x) {
    return 1.0f - 2.0f / (__expf(2.0f * x) + 1.0f);
}

// ---------------- setup kernels (once per launch) ----------------

// Wl -> f16; build concatenated GRU B matrix Bc[g*128+c][k]: k<128 -> wih, else whh
__global__ __launch_bounds__(256) void k_cvt_w(
    const float* __restrict__ Wl, const float* __restrict__ wih,
    const float* __restrict__ whh, _Float16* __restrict__ Wl_h,
    _Float16* __restrict__ Bc) {
    int i = blockIdx.x * 256 + threadIdx.x;          // grid covers 98304
    if (i < N_ETYPES * DF * DF) Wl_h[i] = (_Float16)Wl[i];
    int row = i >> 8;                                // 0..383 = g*128 + c
    int k = i & 255;
    float v = (k < 128) ? wih[row * 128 + k] : whh[row * 128 + (k - 128)];
    Bc[i] = (_Float16)v;
}

__global__ __launch_bounds__(256) void k_cvt_h(
    const float* __restrict__ h, _Float16* __restrict__ hh, int n4) {
    int i = blockIdx.x * 256 + threadIdx.x;
    if (i < n4) {
        float4 v = ((const float4*)h)[i];
        f16x4 o;
        o.x = (_Float16)v.x; o.y = (_Float16)v.y;
        o.z = (_Float16)v.z; o.w = (_Float16)v.w;
        ((f16x4*)hh)[i] = o;
    }
}

__global__ __launch_bounds__(256) void k_hist(
    const int* __restrict__ dst, int* __restrict__ deg, int E) {
    int i = blockIdx.x * 256 + threadIdx.x;
    if (i < E) atomicAdd(&deg[dst[i]], 1);
}

// hierarchical exclusive scan over deg[0..N)
__global__ __launch_bounds__(256) void k_part(
    const int* __restrict__ deg, int* __restrict__ part, int N) {
    __shared__ int s[256];
    int t = threadIdx.x, i = blockIdx.x * 256 + t;
    s[t] = (i < N) ? deg[i] : 0;
    __syncthreads();
    for (int off = 128; off > 0; off >>= 1) {
        if (t < off) s[t] += s[t + off];
        __syncthreads();
    }
    if (t == 0) part[blockIdx.x] = s[0];
}

__global__ __launch_bounds__(256) void k_scan1(int* __restrict__ part, int nb) {
    __shared__ int s[256];
    int t = threadIdx.x;
    int v = (t < nb) ? part[t] : 0;
    s[t] = v;
    __syncthreads();
    for (int off = 1; off < 256; off <<= 1) {
        int u = (t >= off) ? s[t - off] : 0;
        __syncthreads();
        s[t] += u;
        __syncthreads();
    }
    if (t < nb) part[t] = s[t] - v;
}

__global__ __launch_bounds__(256) void k_row(
    const int* __restrict__ deg, const int* __restrict__ part,
    int* __restrict__ row_start, int* __restrict__ cursor, int N) {
    __shared__ int s[256];
    int t = threadIdx.x, i = blockIdx.x * 256 + t;
    int d = (i < N) ? deg[i] : 0;
    s[t] = d;
    __syncthreads();
    for (int off = 1; off < 256; off <<= 1) {
        int u = (t >= off) ? s[t - off] : 0;
        __syncthreads();
        s[t] += u;
        __syncthreads();
    }
    int rs = part[blockIdx.x] + s[t] - d;
    if (i < N) {
        row_start[i] = rs;
        cursor[i] = rs;
        if (i == N - 1) row_start[N] = rs + d;
    }
}

__global__ __launch_bounds__(256) void k_fill(
    const int* __restrict__ src, const int* __restrict__ dst,
    const int* __restrict__ ety, int* __restrict__ cursor,
    int* __restrict__ csr, int E) {
    int i = blockIdx.x * 256 + threadIdx.x;
    if (i < E) {
        int slot = atomicAdd(&cursor[dst[i]], 1);
        csr[slot] = src[i] | ((ety[i] - 1) << 16);   // src < 65536, et in 0..3
    }
}

// ---------------- per-step kernels ----------------

// t[k][n][f] = sum_d h[n,d] * W[k][f,d] + b_lin[k][f]   (f16 h in, f16 out)
// Epilogue: wave-private LDS transpose -> contiguous 1KB dwordx4 stores
// (was 128 scalar 2B stores/lane -> store-issue bound at 830 GB/s).
__global__ __launch_bounds__(256) void k_lin(
    const _Float16* __restrict__ hh, const _Float16* __restrict__ Wl,
    const float* __restrict__ b_lin, _Float16* __restrict__ t_out, int N) {
    __shared__ _Float16 T[4 * 16 * TSTRIDE];
    const int wave = threadIdx.x >> 6, lane = threadIdx.x & 63;
    const int col = lane & 15, quad = lane >> 4;
    const int r0 = blockIdx.x * 64 + wave * 16;
    _Float16* Tw = &T[wave * 16 * TSTRIDE];
    int arow = r0 + col; if (arow >= N) arow = N - 1;
    f16x8 a[4];
    const _Float16* hp = hh + (size_t)arow * DF + quad * 8;
#pragma unroll
    for (int kt = 0; kt < 4; kt++) a[kt] = *(const f16x8*)(hp + kt * 32);
#pragma unroll
    for (int ktype = 0; ktype < N_ETYPES; ktype++) {
        const _Float16* W = Wl + (size_t)ktype * DF * DF;
        _Float16* tk = t_out + (size_t)ktype * N * DF;
        f32x4 accs[8];
#pragma unroll
        for (int ft = 0; ft < 8; ft++) {
            f32x4 acc = {0.f, 0.f, 0.f, 0.f};
            const _Float16* wrow = W + (size_t)(ft * 16 + col) * DF + quad * 8;
#pragma unroll
            for (int kt = 0; kt < 4; kt++)
                acc = __builtin_amdgcn_mfma_f32_16x16x32_f16(
                    a[kt], *(const f16x8*)(wrow + kt * 32), acc, 0, 0, 0);
            accs[ft] = acc;
        }
        // C-layout -> wave-private LDS tile (same-wave RAW/WAR: no barrier needed)
#pragma unroll
        for (int ft = 0; ft < 8; ft++) {
            float bias = b_lin[ktype * DF + ft * 16 + col];
#pragma unroll
            for (int i = 0; i < 4; i++)
                Tw[(quad * 4 + i) * TSTRIDE + ft * 16 + col] = (_Float16)(accs[ft][i] + bias);
        }
        // row-major readback: each wave-store = contiguous 1KB (4 rows x 256B)
        if (r0 < N) {
#pragma unroll
            for (int j = 0; j < 4; j++) {
                int chunk = lane + 64 * j;            // 0..255
                int row = chunk >> 4, c8 = chunk & 15;
                f16x8 v = *(const f16x8*)&Tw[row * TSTRIDE + c8 * 8];
                *(f16x8*)(tk + (size_t)(r0 + row) * DF + c8 * 8) = v;
            }
        }
    }
}

// a[n][:] = sum over incoming edges of t[et][src][:]  -> f16
// wave = 4 edge-slots x 16 lanes; each lane loads f16x8 (16B) = 8 cols.
__global__ __launch_bounds__(256) void k_agg(
    const _Float16* __restrict__ t, const int* __restrict__ row_start,
    const int* __restrict__ csr, _Float16* __restrict__ ah, int N) {
    const int wave = threadIdx.x >> 6, lane = threadIdx.x & 63;
    const int g4 = lane >> 4;                        // edge slot 0..3
    const int c8 = lane & 15;                        // col chunk: cols c8*8..+7
    const int n = blockIdx.x * 4 + wave;             // grid = N/4 exactly
    const int beg = row_start[n], end = row_start[n + 1];
    float acc[8] = {0.f, 0.f, 0.f, 0.f, 0.f, 0.f, 0.f, 0.f};
    for (int e = beg; e < end; e += 8) {
        int i0 = e + g4, i1 = e + 4 + g4;
        float m0 = (i0 < end) ? 1.0f : 0.0f;
        float m1 = (i1 < end) ? 1.0f : 0.0f;
        int j0 = (i0 < end) ? i0 : end - 1;
        int j1 = (i1 < end) ? i1 : end - 1;
        int p0 = csr[j0], p1 = csr[j1];
        f16x8 x0 = *(const f16x8*)(t + ((((size_t)(p0 >> 16)) * N + (p0 & 0xFFFF)) << 7) + c8 * 8);
        f16x8 x1 = *(const f16x8*)(t + ((((size_t)(p1 >> 16)) * N + (p1 & 0xFFFF)) << 7) + c8 * 8);
#pragma unroll
        for (int j = 0; j < 8; j++) acc[j] += m0 * (float)x0[j];
#pragma unroll
        for (int j = 0; j < 8; j++) acc[j] += m1 * (float)x1[j];
    }
#pragma unroll
    for (int j = 0; j < 8; j++) {
        acc[j] += __shfl_xor(acc[j], 32, 64);
        acc[j] += __shfl_xor(acc[j], 16, 64);
    }
    if (lane < 16) {
        f16x8 o;
#pragma unroll
        for (int j = 0; j < 8; j++) o[j] = (_Float16)acc[j];
        *(f16x8*)(ah + ((size_t)n << 7) + c8 * 8) = o;
    }
}

// GRU, gate-parallel: one block per 16-row tile computes ALL 384 output cols.
// 12 waves = 3 gates x 4 col-slices; each wave's B-slice (2x8 frags) persistent
// in VGPRs across the grid-stride task loop. A (ah||h f16, K=256) read once per
// block. Gate accs exchanged through LDS; epilogue fuses gates -> f16 h_next
// (+ fp32 h on the final step).
__global__ __launch_bounds__(768, 3) void k_gru(
    const _Float16* __restrict__ ah, const _Float16* __restrict__ hh,
    const _Float16* __restrict__ Bc, const float* __restrict__ b_ih,
    const float* __restrict__ b_hh, _Float16* __restrict__ hh_next,
    float* __restrict__ out_f32) {
    __shared__ float X[4 * 16 * LSTRIDE];            // [set r,z,in,hn][row][col]
    const int wave = threadIdx.x >> 6, lane = threadIdx.x & 63;
    const int col16 = lane & 15, quad = lane >> 4;
    const int g = wave >> 2;                         // gate 0..2
    const int s = wave & 3;                          // col-slice of 32

    // persistent B fragments: rows (g*128 + s*32 + ct*16 + col16), k = kt*32+quad*8
    f16x8 b[2][8];
#pragma unroll
    for (int ct = 0; ct < 2; ct++) {
        const _Float16* bp = Bc + (((size_t)(g * 128 + s * 32 + ct * 16 + col16)) << 8) + quad * 8;
#pragma unroll
        for (int kt = 0; kt < 8; kt++) b[ct][kt] = *(const f16x8*)(bp + kt * 32);
    }

    for (int tile = blockIdx.x; tile < GRU_TILES; tile += GRU_BLOCKS) {
        const int r0 = tile * 16;                    // 50000 = 16*3125: no row guards
        const int arow = r0 + col16;
        f16x8 A[8];                                  // kt<4 = a, kt>=4 = h
        const _Float16* ap = ah + ((size_t)arow << 7) + quad * 8;
        const _Float16* hp = hh + ((size_t)arow << 7) + quad * 8;
#pragma unroll
        for (int kt = 0; kt < 4; kt++) A[kt] = *(const f16x8*)(ap + kt * 32);
#pragma unroll
        for (int kt = 0; kt < 4; kt++) A[4 + kt] = *(const f16x8*)(hp + kt * 32);

        f32x4 acc[2][2];                             // [khalf-set][ct]; g<2 uses set 0 only
#pragma unroll
        for (int u = 0; u < 2; u++)
#pragma unroll
            for (int ct = 0; ct < 2; ct++) acc[u][ct] = (f32x4){0.f, 0.f, 0.f, 0.f};
#pragma unroll
        for (int kt = 0; kt < 8; kt++) {
            const int set = (g == 2 && kt >= 4) ? 1 : 0;
#pragma unroll
            for (int ct = 0; ct < 2; ct++)
                acc[set][ct] = __builtin_amdgcn_mfma_f32_16x16x32_f16(
                    A[kt], b[ct][kt], acc[set][ct], 0, 0, 0);
        }

        // acc -> LDS exchange
#pragma unroll
        for (int ct = 0; ct < 2; ct++) {
            const int cbase = s * 32 + ct * 16 + col16;
            if (g < 2) {
#pragma unroll
                for (int i = 0; i < 4; i++)
                    X[g * (16 * LSTRIDE) + (quad * 4 + i) * LSTRIDE + cbase] = acc[0][ct][i];
            } else {
#pragma unroll
                for (int i = 0; i < 4; i++) {
                    X[2 * (16 * LSTRIDE) + (quad * 4 + i) * LSTRIDE + cbase] = acc[0][ct][i];
                    X[3 * (16 * LSTRIDE) + (quad * 4 + i) * LSTRIDE + cbase] = acc[1][ct][i];
                }
            }
        }
        __syncthreads();

        // epilogue: 2048 elems over 768 threads
#pragma unroll
        for (int pazz = 0; pazz < 3; pazz++) {
            int e = threadIdx.x + pazz * 768;
            if (e < 2048) {
                int row = e >> 7, col = e & 127;
                float vr = X[0 * (16 * LSTRIDE) + row * LSTRIDE + col];
                float vz = X[1 * (16 * LSTRIDE) + row * LSTRIDE + col];
                float vin = X[2 * (16 * LSTRIDE) + row * LSTRIDE + col];
                float vhn = X[3 * (16 * LSTRIDE) + row * LSTRIDE + col];
                float r = sigmoid_fast(vr + b_ih[col] + b_hh[col]);
                float z = sigmoid_fast(vz + b_ih[128 + col] + b_hh[128 + col]);
                float nn = tanh_fast(vin + b_ih[256 + col] + r * (vhn + b_hh[256 + col]));
                size_t idx = ((size_t)(r0 + row) << 7) + col;
                float hprev = (float)hh[idx];
                float hv = (1.f - z) * nn + z * hprev;
                hh_next[idx] = (_Float16)hv;
                if (out_f32) out_f32[idx] = hv;
            }
        }
        __syncthreads();                             // protect X before next tile's writes
    }
}

// ---------------- launch ----------------

extern "C" void kernel_launch(void* const* d_in, const int* in_sizes, int n_in,
                              void* d_out, int out_size, void* d_ws, size_t ws_size,
                              hipStream_t stream) {
    const float* h0    = (const float*)d_in[0];
    const int*   src   = (const int*)d_in[1];
    const int*   dst   = (const int*)d_in[2];
    const int*   ety   = (const int*)d_in[3];
    const float* W_lin = (const float*)d_in[4];
    const float* b_lin = (const float*)d_in[5];
    const float* w_ih  = (const float*)d_in[6];
    const float* w_hh  = (const float*)d_in[7];
    const float* b_ih  = (const float*)d_in[8];
    const float* b_hh  = (const float*)d_in[9];
    float* hout = (float*)d_out;

    char* p = (char*)d_ws;
    auto alloc = [&](size_t bytes) -> char* {
        char* r = p;
        p += (bytes + 255) & ~(size_t)255;
        return r;
    };
    _Float16* h_a    = (_Float16*)alloc((size_t)N_NODES * DF * 2);
    _Float16* h_b    = (_Float16*)alloc((size_t)N_NODES * DF * 2);
    _Float16* a_half = (_Float16*)alloc((size_t)N_NODES * DF * 2);
    _Float16* t_half = (_Float16*)alloc((size_t)N_ETYPES * N_NODES * DF * 2);
    _Float16* Wl_h   = (_Float16*)alloc((size_t)N_ETYPES * DF * DF * 2);
    _Float16* Bc     = (_Float16*)alloc((size_t)3 * DF * 2 * DF * 2);   // [384][256] f16
    int* deg       = (int*)alloc((size_t)N_NODES * 4);
    int* row_start = (int*)alloc((size_t)(N_NODES + 1) * 4);
    int* cursor    = (int*)alloc((size_t)N_NODES * 4);
    int* csr       = (int*)alloc((size_t)N_EDGES * 4);
    int* part      = (int*)alloc((size_t)SCAN_NB * 4);

    hipMemsetAsync(deg, 0, (size_t)N_NODES * 4, stream);
    k_cvt_w<<<384, 256, 0, stream>>>(W_lin, w_ih, w_hh, Wl_h, Bc);
    k_cvt_h<<<(N_NODES * DF / 4 + 255) / 256, 256, 0, stream>>>(h0, h_a, N_NODES * DF / 4);
    k_hist<<<(N_EDGES + 255) / 256, 256, 0, stream>>>(dst, deg, N_EDGES);
    k_part<<<SCAN_NB, 256, 0, stream>>>(deg, part, N_NODES);
    k_scan1<<<1, 256, 0, stream>>>(part, SCAN_NB);
    k_row<<<SCAN_NB, 256, 0, stream>>>(deg, part, row_start, cursor, N_NODES);
    k_fill<<<(N_EDGES + 255) / 256, 256, 0, stream>>>(src, dst, ety, cursor, csr, N_EDGES);

    _Float16* hc = h_a;
    _Float16* hn = h_b;
    const int nb = (N_NODES + 63) / 64;              // 782
    for (int s = 0; s < N_STEPS; s++) {
        k_lin<<<nb, 256, 0, stream>>>(hc, Wl_h, b_lin, t_half, N_NODES);
        k_agg<<<N_NODES / 4, 256, 0, stream>>>(t_half, row_start, csr, a_half, N_NODES);
        float* of = (s == N_STEPS - 1) ? hout : nullptr;
        k_gru<<<GRU_BLOCKS, 768, 0, stream>>>(a_half, hc, Bc, b_ih, b_hh, hn, of);
        _Float16* tmp = hc; hc = hn; hn = tmp;
    }
}

// Round 7
// 863.832 us; speedup vs baseline: 1.3926x; 1.0541x over previous
//
#include <hip/hip_runtime.h>
#include <hip/hip_bf16.h>
#include <cstdint>
#include <cstddef>

#define N_NODES 50000
#define N_EDGES 600000
#define DF 128
#define N_ETYPES 4
#define N_STEPS 5
#define SCAN_NB 196        // ceil(50000/256)
#define GRU_TILES 3125     // 50000/16 exact
#define GRU_BLOCKS 256     // 1 block/CU
#define LSTRIDE 130        // k_gru LDS row stride (floats): 2-way bank alias only (free)
#define TSTRIDE 136        // k_lin LDS tile row stride (f16)

typedef _Float16 f16x8 __attribute__((ext_vector_type(8)));
typedef _Float16 f16x4 __attribute__((ext_vector_type(4)));
typedef _Float16 f16x2 __attribute__((ext_vector_type(2)));
typedef float f32x4 __attribute__((ext_vector_type(4)));

__device__ __forceinline__ float sigmoid_fast(float x) {
    return 1.0f / (1.0f + __expf(-x));
}
__device__ __forceinline__ float tanh_fast(float x) {
    return 1.0f - 2.0f / (__expf(2.0f * x) + 1.0f);
}

// ---------------- setup kernels (once per launch) ----------------

// Wl -> f16; build concatenated GRU B matrix Bc[g*128+c][k]: k<128 -> wih, else whh
__global__ __launch_bounds__(256) void k_cvt_w(
    const float* __restrict__ Wl, const float* __restrict__ wih,
    const float* __restrict__ whh, _Float16* __restrict__ Wl_h,
    _Float16* __restrict__ Bc) {
    int i = blockIdx.x * 256 + threadIdx.x;          // grid covers 98304
    if (i < N_ETYPES * DF * DF) Wl_h[i] = (_Float16)Wl[i];
    int row = i >> 8;                                // 0..383 = g*128 + c
    int k = i & 255;
    float v = (k < 128) ? wih[row * 128 + k] : whh[row * 128 + (k - 128)];
    Bc[i] = (_Float16)v;
}

__global__ __launch_bounds__(256) void k_cvt_h(
    const float* __restrict__ h, _Float16* __restrict__ hh, int n4) {
    int i = blockIdx.x * 256 + threadIdx.x;
    if (i < n4) {
        float4 v = ((const float4*)h)[i];
        f16x4 o;
        o.x = (_Float16)v.x; o.y = (_Float16)v.y;
        o.z = (_Float16)v.z; o.w = (_Float16)v.w;
        ((f16x4*)hh)[i] = o;
    }
}

__global__ __launch_bounds__(256) void k_hist(
    const int* __restrict__ dst, int* __restrict__ deg, int E) {
    int i = blockIdx.x * 256 + threadIdx.x;
    if (i < E) atomicAdd(&deg[dst[i]], 1);
}

// hierarchical exclusive scan over deg[0..N)
__global__ __launch_bounds__(256) void k_part(
    const int* __restrict__ deg, int* __restrict__ part, int N) {
    __shared__ int s[256];
    int t = threadIdx.x, i = blockIdx.x * 256 + t;
    s[t] = (i < N) ? deg[i] : 0;
    __syncthreads();
    for (int off = 128; off > 0; off >>= 1) {
        if (t < off) s[t] += s[t + off];
        __syncthreads();
    }
    if (t == 0) part[blockIdx.x] = s[0];
}

__global__ __launch_bounds__(256) void k_scan1(int* __restrict__ part, int nb) {
    __shared__ int s[256];
    int t = threadIdx.x;
    int v = (t < nb) ? part[t] : 0;
    s[t] = v;
    __syncthreads();
    for (int off = 1; off < 256; off <<= 1) {
        int u = (t >= off) ? s[t - off] : 0;
        __syncthreads();
        s[t] += u;
        __syncthreads();
    }
    if (t < nb) part[t] = s[t] - v;
}

__global__ __launch_bounds__(256) void k_row(
    const int* __restrict__ deg, const int* __restrict__ part,
    int* __restrict__ row_start, int* __restrict__ cursor, int N) {
    __shared__ int s[256];
    int t = threadIdx.x, i = blockIdx.x * 256 + t;
    int d = (i < N) ? deg[i] : 0;
    s[t] = d;
    __syncthreads();
    for (int off = 1; off < 256; off <<= 1) {
        int u = (t >= off) ? s[t - off] : 0;
        __syncthreads();
        s[t] += u;
        __syncthreads();
    }
    int rs = part[blockIdx.x] + s[t] - d;
    if (i < N) {
        row_start[i] = rs;
        cursor[i] = rs;
        if (i == N - 1) row_start[N] = rs + d;
    }
}

__global__ __launch_bounds__(256) void k_fill(
    const int* __restrict__ src, const int* __restrict__ dst,
    const int* __restrict__ ety, int* __restrict__ cursor,
    int* __restrict__ csr, int E) {
    int i = blockIdx.x * 256 + threadIdx.x;
    if (i < E) {
        int slot = atomicAdd(&cursor[dst[i]], 1);
        csr[slot] = src[i] | ((ety[i] - 1) << 16);   // src < 65536, et in 0..3
    }
}

// ---------------- per-step kernels ----------------

// t[k][n][f] = sum_d h[n,d] * W[k][f,d] + b_lin[k][f]   (f16 h in, f16 out)
// One etype per block (grid.y): 4x the waves of the fused version -> latency
// hiding via TLP; per-etype weights (32 KB) go L1-resident per CU.
// Epilogue: wave-private LDS transpose -> contiguous 1KB dwordx4 stores.
__global__ __launch_bounds__(256) void k_lin(
    const _Float16* __restrict__ hh, const _Float16* __restrict__ Wl,
    const float* __restrict__ b_lin, _Float16* __restrict__ t_out, int N) {
    __shared__ _Float16 T[4 * 16 * TSTRIDE];
    const int wave = threadIdx.x >> 6, lane = threadIdx.x & 63;
    const int col = lane & 15, quad = lane >> 4;
    const int r0 = blockIdx.x * 64 + wave * 16;
    const int ktype = blockIdx.y;
    _Float16* Tw = &T[wave * 16 * TSTRIDE];
    int arow = r0 + col; if (arow >= N) arow = N - 1;
    f16x8 a[4];
    const _Float16* hp = hh + (size_t)arow * DF + quad * 8;
#pragma unroll
    for (int kt = 0; kt < 4; kt++) a[kt] = *(const f16x8*)(hp + kt * 32);
    const _Float16* W = Wl + (size_t)ktype * DF * DF;
    _Float16* tk = t_out + (size_t)ktype * N * DF;
    f32x4 accs[8];
#pragma unroll
    for (int ft = 0; ft < 8; ft++) {
        f32x4 acc = {0.f, 0.f, 0.f, 0.f};
        const _Float16* wrow = W + (size_t)(ft * 16 + col) * DF + quad * 8;
#pragma unroll
        for (int kt = 0; kt < 4; kt++)
            acc = __builtin_amdgcn_mfma_f32_16x16x32_f16(
                a[kt], *(const f16x8*)(wrow + kt * 32), acc, 0, 0, 0);
        accs[ft] = acc;
    }
    // C-layout -> wave-private LDS tile (same-wave RAW/WAR: no barrier needed)
#pragma unroll
    for (int ft = 0; ft < 8; ft++) {
        float bias = b_lin[ktype * DF + ft * 16 + col];
#pragma unroll
        for (int i = 0; i < 4; i++)
            Tw[(quad * 4 + i) * TSTRIDE + ft * 16 + col] = (_Float16)(accs[ft][i] + bias);
    }
    // row-major readback: each wave-store = contiguous 1KB (4 rows x 256B).
    // N % 16 == 0, so a wave's 16 rows are all-in or all-out: r0 guard suffices.
    if (r0 < N) {
#pragma unroll
        for (int j = 0; j < 4; j++) {
            int chunk = lane + 64 * j;               // 0..255
            int row = chunk >> 4, c8 = chunk & 15;
            f16x8 v = *(const f16x8*)&Tw[row * TSTRIDE + c8 * 8];
            *(f16x8*)(tk + (size_t)(r0 + row) * DF + c8 * 8) = v;
        }
    }
}

// a[n][:] = sum over incoming edges of t[et][src][:]  -> f16
// wave = 4 edge-slots x 16 lanes; each lane loads f16x8 (16B) = 8 cols.
// 16 edges (4 independent gather instrs) in flight per iteration.
__global__ __launch_bounds__(256) void k_agg(
    const _Float16* __restrict__ t, const int* __restrict__ row_start,
    const int* __restrict__ csr, _Float16* __restrict__ ah, int N) {
    const int wave = threadIdx.x >> 6, lane = threadIdx.x & 63;
    const int g4 = lane >> 4;                        // edge slot 0..3
    const int c8 = lane & 15;                        // col chunk: cols c8*8..+7
    const int n = blockIdx.x * 4 + wave;             // grid = N/4 exactly
    const int beg = row_start[n], end = row_start[n + 1];
    float acc[8] = {0.f, 0.f, 0.f, 0.f, 0.f, 0.f, 0.f, 0.f};
    for (int e = beg; e < end; e += 16) {
        int i0 = e + g4, i1 = e + 4 + g4, i2 = e + 8 + g4, i3 = e + 12 + g4;
        float m0 = (i0 < end) ? 1.0f : 0.0f;
        float m1 = (i1 < end) ? 1.0f : 0.0f;
        float m2 = (i2 < end) ? 1.0f : 0.0f;
        float m3 = (i3 < end) ? 1.0f : 0.0f;
        int j0 = (i0 < end) ? i0 : end - 1;
        int j1 = (i1 < end) ? i1 : end - 1;
        int j2 = (i2 < end) ? i2 : end - 1;
        int j3 = (i3 < end) ? i3 : end - 1;
        int p0 = csr[j0], p1 = csr[j1], p2 = csr[j2], p3 = csr[j3];
        f16x8 x0 = *(const f16x8*)(t + ((((size_t)(p0 >> 16)) * N + (p0 & 0xFFFF)) << 7) + c8 * 8);
        f16x8 x1 = *(const f16x8*)(t + ((((size_t)(p1 >> 16)) * N + (p1 & 0xFFFF)) << 7) + c8 * 8);
        f16x8 x2 = *(const f16x8*)(t + ((((size_t)(p2 >> 16)) * N + (p2 & 0xFFFF)) << 7) + c8 * 8);
        f16x8 x3 = *(const f16x8*)(t + ((((size_t)(p3 >> 16)) * N + (p3 & 0xFFFF)) << 7) + c8 * 8);
#pragma unroll
        for (int j = 0; j < 8; j++) acc[j] += m0 * (float)x0[j];
#pragma unroll
        for (int j = 0; j < 8; j++) acc[j] += m1 * (float)x1[j];
#pragma unroll
        for (int j = 0; j < 8; j++) acc[j] += m2 * (float)x2[j];
#pragma unroll
        for (int j = 0; j < 8; j++) acc[j] += m3 * (float)x3[j];
    }
#pragma unroll
    for (int j = 0; j < 8; j++) {
        acc[j] += __shfl_xor(acc[j], 32, 64);
        acc[j] += __shfl_xor(acc[j], 16, 64);
    }
    if (lane < 16) {
        f16x8 o;
#pragma unroll
        for (int j = 0; j < 8; j++) o[j] = (_Float16)acc[j];
        *(f16x8*)(ah + ((size_t)n << 7) + c8 * 8) = o;
    }
}

// GRU, gate-parallel: one block per 16-row tile computes ALL 384 output cols.
// 12 waves = 3 gates x 4 col-slices; each wave's B-slice (2x8 frags) persistent
// in VGPRs across the grid-stride task loop. A (ah||h f16, K=256) read once per
// block. Gate accs exchanged through LDS; epilogue fuses gates -> f16 h_next
// (+ fp32 h on the final step).
__global__ __launch_bounds__(768, 3) void k_gru(
    const _Float16* __restrict__ ah, const _Float16* __restrict__ hh,
    const _Float16* __restrict__ Bc, const float* __restrict__ b_ih,
    const float* __restrict__ b_hh, _Float16* __restrict__ hh_next,
    float* __restrict__ out_f32) {
    __shared__ float X[4 * 16 * LSTRIDE];            // [set r,z,in,hn][row][col]
    const int wave = threadIdx.x >> 6, lane = threadIdx.x & 63;
    const int col16 = lane & 15, quad = lane >> 4;
    const int g = wave >> 2;                         // gate 0..2
    const int s = wave & 3;                          // col-slice of 32

    // persistent B fragments: rows (g*128 + s*32 + ct*16 + col16), k = kt*32+quad*8
    f16x8 b[2][8];
#pragma unroll
    for (int ct = 0; ct < 2; ct++) {
        const _Float16* bp = Bc + (((size_t)(g * 128 + s * 32 + ct * 16 + col16)) << 8) + quad * 8;
#pragma unroll
        for (int kt = 0; kt < 8; kt++) b[ct][kt] = *(const f16x8*)(bp + kt * 32);
    }

    for (int tile = blockIdx.x; tile < GRU_TILES; tile += GRU_BLOCKS) {
        const int r0 = tile * 16;                    // 50000 = 16*3125: no row guards
        const int arow = r0 + col16;
        f16x8 A[8];                                  // kt<4 = a, kt>=4 = h
        const _Float16* ap = ah + ((size_t)arow << 7) + quad * 8;
        const _Float16* hp = hh + ((size_t)arow << 7) + quad * 8;
#pragma unroll
        for (int kt = 0; kt < 4; kt++) A[kt] = *(const f16x8*)(ap + kt * 32);
#pragma unroll
        for (int kt = 0; kt < 4; kt++) A[4 + kt] = *(const f16x8*)(hp + kt * 32);

        f32x4 acc[2][2];                             // [khalf-set][ct]; g<2 uses set 0 only
#pragma unroll
        for (int u = 0; u < 2; u++)
#pragma unroll
            for (int ct = 0; ct < 2; ct++) acc[u][ct] = (f32x4){0.f, 0.f, 0.f, 0.f};
#pragma unroll
        for (int kt = 0; kt < 8; kt++) {
            const int set = (g == 2 && kt >= 4) ? 1 : 0;
#pragma unroll
            for (int ct = 0; ct < 2; ct++)
                acc[set][ct] = __builtin_amdgcn_mfma_f32_16x16x32_f16(
                    A[kt], b[ct][kt], acc[set][ct], 0, 0, 0);
        }

        // acc -> LDS exchange
#pragma unroll
        for (int ct = 0; ct < 2; ct++) {
            const int cbase = s * 32 + ct * 16 + col16;
            if (g < 2) {
#pragma unroll
                for (int i = 0; i < 4; i++)
                    X[g * (16 * LSTRIDE) + (quad * 4 + i) * LSTRIDE + cbase] = acc[0][ct][i];
            } else {
#pragma unroll
                for (int i = 0; i < 4; i++) {
                    X[2 * (16 * LSTRIDE) + (quad * 4 + i) * LSTRIDE + cbase] = acc[0][ct][i];
                    X[3 * (16 * LSTRIDE) + (quad * 4 + i) * LSTRIDE + cbase] = acc[1][ct][i];
                }
            }
        }
        __syncthreads();

        // epilogue: 2048 elems over 768 threads
#pragma unroll
        for (int pazz = 0; pazz < 3; pazz++) {
            int e = threadIdx.x + pazz * 768;
            if (e < 2048) {
                int row = e >> 7, col = e & 127;
                float vr = X[0 * (16 * LSTRIDE) + row * LSTRIDE + col];
                float vz = X[1 * (16 * LSTRIDE) + row * LSTRIDE + col];
                float vin = X[2 * (16 * LSTRIDE) + row * LSTRIDE + col];
                float vhn = X[3 * (16 * LSTRIDE) + row * LSTRIDE + col];
                float r = sigmoid_fast(vr + b_ih[col] + b_hh[col]);
                float z = sigmoid_fast(vz + b_ih[128 + col] + b_hh[128 + col]);
                float nn = tanh_fast(vin + b_ih[256 + col] + r * (vhn + b_hh[256 + col]));
                size_t idx = ((size_t)(r0 + row) << 7) + col;
                float hprev = (float)hh[idx];
                float hv = (1.f - z) * nn + z * hprev;
                hh_next[idx] = (_Float16)hv;
                if (out_f32) out_f32[idx] = hv;
            }
        }
        __syncthreads();                             // protect X before next tile's writes
    }
}

// ---------------- launch ----------------

extern "C" void kernel_launch(void* const* d_in, const int* in_sizes, int n_in,
                              void* d_out, int out_size, void* d_ws, size_t ws_size,
                              hipStream_t stream) {
    const float* h0    = (const float*)d_in[0];
    const int*   src   = (const int*)d_in[1];
    const int*   dst   = (const int*)d_in[2];
    const int*   ety   = (const int*)d_in[3];
    const float* W_lin = (const float*)d_in[4];
    const float* b_lin = (const float*)d_in[5];
    const float* w_ih  = (const float*)d_in[6];
    const float* w_hh  = (const float*)d_in[7];
    const float* b_ih  = (const float*)d_in[8];
    const float* b_hh  = (const float*)d_in[9];
    float* hout = (float*)d_out;

    char* p = (char*)d_ws;
    auto alloc = [&](size_t bytes) -> char* {
        char* r = p;
        p += (bytes + 255) & ~(size_t)255;
        return r;
    };
    _Float16* h_a    = (_Float16*)alloc((size_t)N_NODES * DF * 2);
    _Float16* h_b    = (_Float16*)alloc((size_t)N_NODES * DF * 2);
    _Float16* a_half = (_Float16*)alloc((size_t)N_NODES * DF * 2);
    _Float16* t_half = (_Float16*)alloc((size_t)N_ETYPES * N_NODES * DF * 2);
    _Float16* Wl_h   = (_Float16*)alloc((size_t)N_ETYPES * DF * DF * 2);
    _Float16* Bc     = (_Float16*)alloc((size_t)3 * DF * 2 * DF * 2);   // [384][256] f16
    int* deg       = (int*)alloc((size_t)N_NODES * 4);
    int* row_start = (int*)alloc((size_t)(N_NODES + 1) * 4);
    int* cursor    = (int*)alloc((size_t)N_NODES * 4);
    int* csr       = (int*)alloc((size_t)N_EDGES * 4);
    int* part      = (int*)alloc((size_t)SCAN_NB * 4);

    hipMemsetAsync(deg, 0, (size_t)N_NODES * 4, stream);
    k_cvt_w<<<384, 256, 0, stream>>>(W_lin, w_ih, w_hh, Wl_h, Bc);
    k_cvt_h<<<(N_NODES * DF / 4 + 255) / 256, 256, 0, stream>>>(h0, h_a, N_NODES * DF / 4);
    k_hist<<<(N_EDGES + 255) / 256, 256, 0, stream>>>(dst, deg, N_EDGES);
    k_part<<<SCAN_NB, 256, 0, stream>>>(deg, part, N_NODES);
    k_scan1<<<1, 256, 0, stream>>>(part, SCAN_NB);
    k_row<<<SCAN_NB, 256, 0, stream>>>(deg, part, row_start, cursor, N_NODES);
    k_fill<<<(N_EDGES + 255) / 256, 256, 0, stream>>>(src, dst, ety, cursor, csr, N_EDGES);

    _Float16* hc = h_a;
    _Float16* hn = h_b;
    const int nb = (N_NODES + 63) / 64;              // 782
    for (int s = 0; s < N_STEPS; s++) {
        k_lin<<<dim3(nb, N_ETYPES), 256, 0, stream>>>(hc, Wl_h, b_lin, t_half, N_NODES);
        k_agg<<<N_NODES / 4, 256, 0, stream>>>(t_half, row_start, csr, a_half, N_NODES);
        float* of = (s == N_STEPS - 1) ? hout : nullptr;
        k_gru<<<GRU_BLOCKS, 768, 0, stream>>>(a_half, hc, Bc, b_ih, b_hh, hn, of);
        _Float16* tmp = hc; hc = hn; hn = tmp;
    }
}